// Round 12
// baseline (742.867 us; speedup 1.0000x reference)
//
#include <hip/hip_runtime.h>

#define B_ 4
#define S_ 4096
#define D_ 1024
#define E_ 8
#define I_ 2048
#define K_ 1024

typedef __attribute__((ext_vector_type(8))) short short8;
typedef __attribute__((ext_vector_type(16))) float f32x16;

__device__ __forceinline__ short f2bf(float f) {
  union { float f; unsigned u; } v; v.f = f;
  unsigned r = v.u + 0x7FFFu + ((v.u >> 16) & 1u);
  return (short)(r >> 16);
}

__device__ __forceinline__ void gload16(const void* g, void* l) {
  __builtin_amdgcn_global_load_lds((const __attribute__((address_space(1))) unsigned int*)g,
                                   (__attribute__((address_space(3))) unsigned int*)l, 16, 0, 0);
}

// swizzled LDS fragment read: tile rows are 128 bytes, byte col XORed by ((row&7)<<4)
__device__ __forceinline__ short8 rdswz(const short* ls, int row, int cb) {
  int byte = (row << 7) + (cb ^ ((row & 7) << 4));
  return *reinterpret_cast<const short8*>(reinterpret_cast<const char*>(ls) + byte);
}

// ---------------- Router: logits + softmax in f64, one wave per token ----------------
__global__ __launch_bounds__(256) void router_kernel(const float* __restrict__ x,
                                                     const float* __restrict__ gw,
                                                     double* __restrict__ affD) {
  int wave = threadIdx.x >> 6, lane = threadIdx.x & 63;
  int tok = blockIdx.x * 4 + wave;          // tok = b*S + s
  int b = tok >> 12, s = tok & (S_ - 1);
  const float* xr = x + (size_t)tok * D_;
  double acc[E_];
#pragma unroll
  for (int e = 0; e < E_; ++e) acc[e] = 0.0;
#pragma unroll 4
  for (int r = 0; r < 16; ++r) {
    int d = r * 64 + lane;
    float xv = xr[d];
    const float4* g4 = reinterpret_cast<const float4*>(gw + (size_t)d * E_);
    float4 g0 = g4[0], g1 = g4[1];
    acc[0] += (double)xv * g0.x; acc[1] += (double)xv * g0.y;
    acc[2] += (double)xv * g0.z; acc[3] += (double)xv * g0.w;
    acc[4] += (double)xv * g1.x; acc[5] += (double)xv * g1.y;
    acc[6] += (double)xv * g1.z; acc[7] += (double)xv * g1.w;
  }
#pragma unroll
  for (int off = 32; off > 0; off >>= 1) {
#pragma unroll
    for (int e = 0; e < E_; ++e) acc[e] += __shfl_xor(acc[e], off, 64);
  }
  double m = acc[0];
#pragma unroll
  for (int e = 1; e < E_; ++e) m = acc[e] > m ? acc[e] : m;
  double den = 0.0, ex[E_];
#pragma unroll
  for (int e = 0; e < E_; ++e) { ex[e] = exp(acc[e] - m); den += ex[e]; }
  if (lane < E_)
    affD[((size_t)b * E_ + lane) * S_ + s] = ex[lane] / den;
}

// ---------------- Top-K per (b,e): 8-pass radix select on composite u64 keys ----------------
__global__ __launch_bounds__(1024) void topk_select_kernel(const double* __restrict__ affD,
                                                           int* __restrict__ idxArr,
                                                           float* __restrict__ gateArr) {
  __shared__ unsigned hist[256];
  __shared__ unsigned s_digit;
  __shared__ int s_rem;
  __shared__ unsigned s_cnt;
  int be = blockIdx.x, tid = threadIdx.x;
  const double* a = affD + (size_t)be * S_;
  unsigned long long key[4];
  bool active[4];
#pragma unroll
  for (int c = 0; c < 4; ++c) {
    int i = tid + c * 1024;
    unsigned long long kb = (unsigned long long)__double_as_longlong(a[i]);
    key[c] = (kb & ~0xFFFULL) | (unsigned long long)(4095 - i);
    active[c] = true;
  }
  int remk = K_;
  unsigned long long prefix = 0;
  for (int pass = 0; pass < 8; ++pass) {
    int shift = 56 - pass * 8;
    if (tid < 256) hist[tid] = 0;
    __syncthreads();
#pragma unroll
    for (int c = 0; c < 4; ++c)
      if (active[c]) atomicAdd(&hist[(unsigned)((key[c] >> shift) & 0xFF)], 1u);
    __syncthreads();
    if (tid == 0) {
      unsigned cum = 0; int d = 255;
      for (; d > 0; --d) {
        unsigned h = hist[d];
        if (cum + h >= (unsigned)remk) break;
        cum += h;
      }
      s_digit = (unsigned)d;
      s_rem = remk - (int)cum;
    }
    __syncthreads();
    unsigned dg = s_digit; remk = s_rem;
    prefix |= ((unsigned long long)dg) << shift;
#pragma unroll
    for (int c = 0; c < 4; ++c)
      active[c] = active[c] && (((key[c] >> shift) & 0xFF) == dg);
    __syncthreads();
  }
  if (tid == 0) s_cnt = 0;
  __syncthreads();
#pragma unroll
  for (int c = 0; c < 4; ++c) {
    if (key[c] >= prefix) {
      unsigned slot = atomicAdd(&s_cnt, 1u);
      int i = 4095 - (int)(key[c] & 0xFFF);
      idxArr[(size_t)be * K_ + slot] = i;
      gateArr[(size_t)be * K_ + slot] = (float)a[i];
    }
  }
}

// ---------- All-weights transpose + cvt: y picks {Wg,Wu: [D][I]->[I][D]; Wd: [I][D]->[D][I]} ----------
__global__ __launch_bounds__(256) void transpose_cvt3_kernel(const float* __restrict__ Wg,
                                                             const float* __restrict__ Wu,
                                                             const float* __restrict__ Wd,
                                                             unsigned short* __restrict__ WgT,
                                                             unsigned short* __restrict__ WuT,
                                                             unsigned short* __restrict__ WdT) {
  __shared__ float t[64][65];
  int wsel = blockIdx.y >> 3;       // 0..2
  int e = blockIdx.y & 7;
  const float* in = wsel == 0 ? Wg : (wsel == 1 ? Wu : Wd);
  unsigned short* out = wsel == 0 ? WgT : (wsel == 1 ? WuT : WdT);
  int M = wsel == 2 ? I_ : D_;
  int N = wsel == 2 ? D_ : I_;
  int ntn = N >> 6;
  int tm = (blockIdx.x / ntn) << 6;
  int tn = (blockIdx.x % ntn) << 6;
  const float* src = in + (size_t)e * M * N;
  unsigned short* dst = out + (size_t)e * M * N;
  int tid = threadIdx.x;
#pragma unroll
  for (int it = 0; it < 4; ++it) {
    int f = it * 256 + tid;
    int r = f >> 4, c4 = (f & 15) << 2;
    float4 v = *reinterpret_cast<const float4*>(&src[(size_t)(tm + r) * N + tn + c4]);
    t[c4][r] = v.x; t[c4 + 1][r] = v.y; t[c4 + 2][r] = v.z; t[c4 + 3][r] = v.w;
  }
  __syncthreads();
#pragma unroll
  for (int it = 0; it < 4; ++it) {
    int f = it * 256 + tid;
    int rr = f >> 4, c4 = (f & 15) << 2;
    short4 o;
    o.x = f2bf(t[rr][c4]); o.y = f2bf(t[rr][c4 + 1]);
    o.z = f2bf(t[rr][c4 + 2]); o.w = f2bf(t[rr][c4 + 3]);
    *reinterpret_cast<short4*>(&dst[(size_t)(tn + rr) * M + tm + c4]) = o;
  }
}

// ---------------- Gather selected tokens + cvt to bf16: Xsel[be][k][d] ----------------
__global__ __launch_bounds__(256) void gather_cvt_kernel(const float* __restrict__ x,
                                                         const int* __restrict__ idxArr,
                                                         unsigned short* __restrict__ Xsel) {
  int row = blockIdx.x * 4 + (threadIdx.x >> 6);  // be*K_ + k
  int lane = threadIdx.x & 63;
  int b = row >> 13;                              // be>>3
  int tok = idxArr[row];
  const float* src = x + ((size_t)b * S_ + tok) * D_;
  unsigned short* dst = Xsel + (size_t)row * D_;
#pragma unroll
  for (int it = 0; it < 4; ++it) {
    int d = it * 256 + lane * 4;
    float4 v = *reinterpret_cast<const float4*>(src + d);
    short4 o;
    o.x = f2bf(v.x); o.y = f2bf(v.y); o.z = f2bf(v.z); o.w = f2bf(v.w);
    *reinterpret_cast<short4*>(dst + d) = o;
  }
}

// ---------------- Stage 1: H = silu(Xsel@Wg) * (Xsel@Wu), 32x32x16 MFMA ----------------
// kc selects token half: rows [kc*512, kc*512+512). H layout [be][512][I_].
__global__ __launch_bounds__(256, 2) void mlp1_kernel(
    const unsigned short* __restrict__ Xsel, const unsigned short* __restrict__ WgT,
    const unsigned short* __restrict__ WuT, unsigned short* __restrict__ H, int kc) {
  int nwg = gridDim.x;
  int bid = (blockIdx.x & 7) * (nwg >> 3) + (blockIdx.x >> 3);  // XCD swizzle (nwg%8==0)
  int nt = bid & 15; bid >>= 4;        // 16 I-tiles of 128
  int mt = bid & 3; bid >>= 2;         // 4 token-tiles of 128
  int be = bid;
  int e = be & 7;

  __shared__ short lsA[128 * 64];
  __shared__ short lsBg[128 * 64];
  __shared__ short lsBu[128 * 64];

  int tid = threadIdx.x, w = tid >> 6, lane = tid & 63;
  int wm = w >> 1, wn = w & 1;
  int l31 = lane & 31, lgh = lane >> 5;

  int srow = lane >> 3;                      // row within 8-row chunk
  int scol = ((lane & 7) ^ srow) << 4;       // pre-swizzled source byte col

  const char* pa = (const char*)(Xsel + ((size_t)be * K_ + kc * 512 + mt * 128) * D_);
  const char* pg = (const char*)(WgT + ((size_t)e * I_ + nt * 128) * D_);
  const char* pu = (const char*)(WuT + ((size_t)e * I_ + nt * 128) * D_);

  f32x16 accg[2][2], accu[2][2];
#pragma unroll
  for (int i = 0; i < 2; ++i)
#pragma unroll
    for (int j = 0; j < 2; ++j) {
      accg[i][j] = (f32x16)(0.f);
      accu[i][j] = (f32x16)(0.f);
    }

  for (int k0 = 0; k0 < D_; k0 += 64) {
#pragma unroll
    for (int c = 0; c < 4; ++c) {
      int chunk = c * 4 + w;                 // wave-uniform
      int row = chunk * 8 + srow;
      size_t go = (size_t)row * (D_ * 2) + (size_t)k0 * 2 + scol;
      gload16(pa + go, (char*)lsA + chunk * 1024);
      gload16(pg + go, (char*)lsBg + chunk * 1024);
      gload16(pu + go, (char*)lsBu + chunk * 1024);
    }
    __syncthreads();
#pragma unroll
    for (int ks = 0; ks < 4; ++ks) {
      int cb = ks * 32 + lgh * 16;
      short8 af[2], bgf[2], buf[2];
#pragma unroll
      for (int mf = 0; mf < 2; ++mf)
        af[mf] = rdswz(lsA, wm * 64 + mf * 32 + l31, cb);
#pragma unroll
      for (int nf = 0; nf < 2; ++nf) {
        bgf[nf] = rdswz(lsBg, wn * 64 + nf * 32 + l31, cb);
        buf[nf] = rdswz(lsBu, wn * 64 + nf * 32 + l31, cb);
      }
#pragma unroll
      for (int mf = 0; mf < 2; ++mf)
#pragma unroll
        for (int nf = 0; nf < 2; ++nf) {
          accg[mf][nf] = __builtin_amdgcn_mfma_f32_32x32x16_bf16(af[mf], bgf[nf], accg[mf][nf], 0, 0, 0);
          accu[mf][nf] = __builtin_amdgcn_mfma_f32_32x32x16_bf16(af[mf], buf[nf], accu[mf][nf], 0, 0, 0);
        }
    }
    __syncthreads();
  }
  // epilogue: h = silu(g)*u -> bf16 H[be][512][I_]
  // C/D map (32x32): col = lane&31, row = (r&3) + 8*(r>>2) + 4*(lane>>5)
  unsigned short* Hbe = H + (size_t)be * 512 * I_;
#pragma unroll
  for (int mf = 0; mf < 2; ++mf)
#pragma unroll
    for (int nf = 0; nf < 2; ++nf) {
#pragma unroll
      for (int r = 0; r < 16; ++r) {
        float g = accg[mf][nf][r], u = accu[mf][nf][r];
        float h = g / (1.f + __expf(-g)) * u;
        int rowl = (r & 3) + 8 * (r >> 2) + 4 * lgh;
        int row = wm * 64 + mf * 32 + rowl;
        int col = wn * 64 + nf * 32 + l31;
        Hbe[(size_t)(mt * 128 + row) * I_ + nt * 128 + col] = (unsigned short)f2bf(h);
      }
    }
}

// ---------- Stage 2: Out += gate * (H @ Wd), 128x256 tile, 32x32x16 MFMA ----------
__global__ __launch_bounds__(256, 2) void mlp2_kernel(
    const unsigned short* __restrict__ H, const unsigned short* __restrict__ WdT,
    const int* __restrict__ idxArr, const float* __restrict__ gateArr,
    float* __restrict__ out, int kc) {
  int nwg = gridDim.x;
  int bid = (blockIdx.x & 7) * (nwg >> 3) + (blockIdx.x >> 3);  // XCD swizzle
  int nt = bid & 3; bid >>= 2;         // 4 D-tiles of 256
  int mt = bid & 3; bid >>= 2;         // 4 token-tiles of 128
  int be = bid;
  int b = be >> 3, e = be & 7;

  __shared__ short lsA[128 * 64];
  __shared__ short lsB[256 * 64];
  __shared__ int sTok[128];
  __shared__ float sGate[128];

  int tid = threadIdx.x;
  if (tid < 128) {
    size_t gbase = (size_t)be * K_ + kc * 512 + mt * 128 + tid;
    sTok[tid] = idxArr[gbase];
    sGate[tid] = gateArr[gbase];
  }

  const char* pa = (const char*)(H + ((size_t)be * 512 + mt * 128) * I_);
  const char* pb = (const char*)(WdT + ((size_t)e * D_ + nt * 256) * I_);

  int w = tid >> 6, lane = tid & 63;
  int wm = w >> 1, wn = w & 1;
  int l31 = lane & 31, lgh = lane >> 5;

  int srow = lane >> 3;
  int scol = ((lane & 7) ^ srow) << 4;

  f32x16 acc[2][4];
#pragma unroll
  for (int i = 0; i < 2; ++i)
#pragma unroll
    for (int j = 0; j < 4; ++j) acc[i][j] = (f32x16)(0.f);

  for (int k0 = 0; k0 < I_; k0 += 64) {
#pragma unroll
    for (int c = 0; c < 4; ++c) {          // A: 16 chunks of 8 rows
      int chunk = c * 4 + w;
      int row = chunk * 8 + srow;
      gload16(pa + (size_t)row * (I_ * 2) + (size_t)k0 * 2 + scol, (char*)lsA + chunk * 1024);
    }
#pragma unroll
    for (int c = 0; c < 8; ++c) {          // B: 32 chunks of 8 rows
      int chunk = c * 4 + w;
      int row = chunk * 8 + srow;
      gload16(pb + (size_t)row * (I_ * 2) + (size_t)k0 * 2 + scol, (char*)lsB + chunk * 1024);
    }
    __syncthreads();
#pragma unroll
    for (int ks = 0; ks < 4; ++ks) {
      int cb = ks * 32 + lgh * 16;
      short8 af[2], bf[4];
#pragma unroll
      for (int mf = 0; mf < 2; ++mf)
        af[mf] = rdswz(lsA, wm * 64 + mf * 32 + l31, cb);
#pragma unroll
      for (int nf = 0; nf < 4; ++nf)
        bf[nf] = rdswz(lsB, wn * 128 + nf * 32 + l31, cb);
#pragma unroll
      for (int mf = 0; mf < 2; ++mf)
#pragma unroll
        for (int nf = 0; nf < 4; ++nf)
          acc[mf][nf] = __builtin_amdgcn_mfma_f32_32x32x16_bf16(af[mf], bf[nf], acc[mf][nf], 0, 0, 0);
    }
    __syncthreads();
  }
  // epilogue: weighted scatter-add (once per token per kc half)
#pragma unroll
  for (int mf = 0; mf < 2; ++mf)
#pragma unroll
    for (int nf = 0; nf < 4; ++nf) {
#pragma unroll
      for (int r = 0; r < 16; ++r) {
        int rowl = (r & 3) + 8 * (r >> 2) + 4 * lgh;
        int row = wm * 64 + mf * 32 + rowl;
        int col = nt * 256 + wn * 128 + nf * 32 + l31;
        float v = acc[mf][nf][r] * sGate[row];
        atomicAdd(&out[((size_t)b * S_ + sTok[row]) * D_ + col], v);
      }
    }
}

extern "C" void kernel_launch(void* const* d_in, const int* in_sizes, int n_in,
                              void* d_out, int out_size, void* d_ws, size_t ws_size,
                              hipStream_t stream) {
  const float* x  = (const float*)d_in[0];
  const float* gw = (const float*)d_in[1];
  const float* Wg = (const float*)d_in[2];
  const float* Wu = (const float*)d_in[3];
  const float* Wd = (const float*)d_in[4];
  float* out = (float*)d_out;
  char* ws = (char*)d_ws;

  size_t off = 0;
  double* affD = (double*)(ws + off); off += (size_t)B_ * E_ * S_ * sizeof(double);  // 1 MB
  int* idxArr = (int*)(ws + off);     off += (size_t)B_ * E_ * K_ * sizeof(int);     // 128 KB
  float* gateArr = (float*)(ws + off); off += (size_t)B_ * E_ * K_ * sizeof(float);  // 128 KB
  off = (off + 255) & ~(size_t)255;
  unsigned short* WgT = (unsigned short*)(ws + off); off += (size_t)E_ * D_ * I_ * 2; // 32 MB
  unsigned short* WuT = (unsigned short*)(ws + off); off += (size_t)E_ * D_ * I_ * 2; // 32 MB
  unsigned short* WdT = (unsigned short*)(ws + off); off += (size_t)E_ * D_ * I_ * 2; // 32 MB
  unsigned short* Xsel = (unsigned short*)(ws + off); off += (size_t)B_ * E_ * K_ * D_ * 2; // 64 MB
  off = (off + 255) & ~(size_t)255;
  unsigned short* H = (unsigned short*)(ws + off);   // 64 MB: [32 be][512 tok][2048 I]

  hipMemsetAsync(d_out, 0, (size_t)out_size * sizeof(float), stream);
  router_kernel<<<B_ * S_ / 4, 256, 0, stream>>>(x, gw, affD);
  topk_select_kernel<<<B_ * E_, 1024, 0, stream>>>(affD, idxArr, gateArr);
  transpose_cvt3_kernel<<<dim3((D_ / 64) * (I_ / 64), 3 * E_), 256, 0, stream>>>(
      Wg, Wu, Wd, WgT, WuT, WdT);
  gather_cvt_kernel<<<B_ * E_ * K_ / 4, 256, 0, stream>>>(x, idxArr, Xsel);
  for (int kc = 0; kc < 2; ++kc) {
    mlp1_kernel<<<B_ * E_ * 4 * 16, 256, 0, stream>>>(Xsel, WgT, WuT, H, kc);
    mlp2_kernel<<<B_ * E_ * 4 * 4, 256, 0, stream>>>(H, WdT, idxArr, gateArr, out, kc);
  }
}

// Round 13
// 712.144 us; speedup vs baseline: 1.0431x; 1.0431x over previous
//
#include <hip/hip_runtime.h>

#define B_ 4
#define S_ 4096
#define D_ 1024
#define E_ 8
#define I_ 2048
#define K_ 1024

typedef __attribute__((ext_vector_type(8))) short short8;
typedef __attribute__((ext_vector_type(4))) float f32x4;

__device__ __forceinline__ short f2bf(float f) {
  union { float f; unsigned u; } v; v.f = f;
  unsigned r = v.u + 0x7FFFu + ((v.u >> 16) & 1u);
  return (short)(r >> 16);
}

__device__ __forceinline__ void gload16(const void* g, void* l) {
  __builtin_amdgcn_global_load_lds((const __attribute__((address_space(1))) unsigned int*)g,
                                   (__attribute__((address_space(3))) unsigned int*)l, 16, 0, 0);
}

// swizzled LDS fragment read: tile rows are 128 bytes, byte col XORed by ((row&7)<<4)
__device__ __forceinline__ short8 rdswz(const short* ls, int row, int cb) {
  int byte = (row << 7) + (cb ^ ((row & 7) << 4));
  return *reinterpret_cast<const short8*>(reinterpret_cast<const char*>(ls) + byte);
}

// ---------------- Router: logits + softmax in f64, one wave per token ----------------
__global__ __launch_bounds__(256) void router_kernel(const float* __restrict__ x,
                                                     const float* __restrict__ gw,
                                                     double* __restrict__ affD) {
  int wave = threadIdx.x >> 6, lane = threadIdx.x & 63;
  int tok = blockIdx.x * 4 + wave;          // tok = b*S + s
  int b = tok >> 12, s = tok & (S_ - 1);
  const float* xr = x + (size_t)tok * D_;
  double acc[E_];
#pragma unroll
  for (int e = 0; e < E_; ++e) acc[e] = 0.0;
#pragma unroll 4
  for (int r = 0; r < 16; ++r) {
    int d = r * 64 + lane;
    float xv = xr[d];
    const float4* g4 = reinterpret_cast<const float4*>(gw + (size_t)d * E_);
    float4 g0 = g4[0], g1 = g4[1];
    acc[0] += (double)xv * g0.x; acc[1] += (double)xv * g0.y;
    acc[2] += (double)xv * g0.z; acc[3] += (double)xv * g0.w;
    acc[4] += (double)xv * g1.x; acc[5] += (double)xv * g1.y;
    acc[6] += (double)xv * g1.z; acc[7] += (double)xv * g1.w;
  }
#pragma unroll
  for (int off = 32; off > 0; off >>= 1) {
#pragma unroll
    for (int e = 0; e < E_; ++e) acc[e] += __shfl_xor(acc[e], off, 64);
  }
  double m = acc[0];
#pragma unroll
  for (int e = 1; e < E_; ++e) m = acc[e] > m ? acc[e] : m;
  double den = 0.0, ex[E_];
#pragma unroll
  for (int e = 0; e < E_; ++e) { ex[e] = exp(acc[e] - m); den += ex[e]; }
  if (lane < E_)
    affD[((size_t)b * E_ + lane) * S_ + s] = ex[lane] / den;
}

// ---------------- Top-K per (b,e): 8-pass radix select on composite u64 keys ----------------
__global__ __launch_bounds__(1024) void topk_select_kernel(const double* __restrict__ affD,
                                                           int* __restrict__ idxArr,
                                                           float* __restrict__ gateArr) {
  __shared__ unsigned hist[256];
  __shared__ unsigned s_digit;
  __shared__ int s_rem;
  __shared__ unsigned s_cnt;
  int be = blockIdx.x, tid = threadIdx.x;
  const double* a = affD + (size_t)be * S_;
  unsigned long long key[4];
  bool active[4];
#pragma unroll
  for (int c = 0; c < 4; ++c) {
    int i = tid + c * 1024;
    unsigned long long kb = (unsigned long long)__double_as_longlong(a[i]);
    key[c] = (kb & ~0xFFFULL) | (unsigned long long)(4095 - i);
    active[c] = true;
  }
  int remk = K_;
  unsigned long long prefix = 0;
  for (int pass = 0; pass < 8; ++pass) {
    int shift = 56 - pass * 8;
    if (tid < 256) hist[tid] = 0;
    __syncthreads();
#pragma unroll
    for (int c = 0; c < 4; ++c)
      if (active[c]) atomicAdd(&hist[(unsigned)((key[c] >> shift) & 0xFF)], 1u);
    __syncthreads();
    if (tid == 0) {
      unsigned cum = 0; int d = 255;
      for (; d > 0; --d) {
        unsigned h = hist[d];
        if (cum + h >= (unsigned)remk) break;
        cum += h;
      }
      s_digit = (unsigned)d;
      s_rem = remk - (int)cum;
    }
    __syncthreads();
    unsigned dg = s_digit; remk = s_rem;
    prefix |= ((unsigned long long)dg) << shift;
#pragma unroll
    for (int c = 0; c < 4; ++c)
      active[c] = active[c] && (((key[c] >> shift) & 0xFF) == dg);
    __syncthreads();
  }
  if (tid == 0) s_cnt = 0;
  __syncthreads();
#pragma unroll
  for (int c = 0; c < 4; ++c) {
    if (key[c] >= prefix) {
      unsigned slot = atomicAdd(&s_cnt, 1u);
      int i = 4095 - (int)(key[c] & 0xFFF);
      idxArr[(size_t)be * K_ + slot] = i;
      gateArr[(size_t)be * K_ + slot] = (float)a[i];
    }
  }
}

// ---------- All-weights transpose + cvt: y picks {Wg,Wu: [D][I]->[I][D]; Wd: [I][D]->[D][I]} ----------
__global__ __launch_bounds__(256) void transpose_cvt3_kernel(const float* __restrict__ Wg,
                                                             const float* __restrict__ Wu,
                                                             const float* __restrict__ Wd,
                                                             unsigned short* __restrict__ WgT,
                                                             unsigned short* __restrict__ WuT,
                                                             unsigned short* __restrict__ WdT) {
  __shared__ float t[64][65];
  int wsel = blockIdx.y >> 3;       // 0..2
  int e = blockIdx.y & 7;
  const float* in = wsel == 0 ? Wg : (wsel == 1 ? Wu : Wd);
  unsigned short* out = wsel == 0 ? WgT : (wsel == 1 ? WuT : WdT);
  int M = wsel == 2 ? I_ : D_;
  int N = wsel == 2 ? D_ : I_;
  int ntn = N >> 6;
  int tm = (blockIdx.x / ntn) << 6;
  int tn = (blockIdx.x % ntn) << 6;
  const float* src = in + (size_t)e * M * N;
  unsigned short* dst = out + (size_t)e * M * N;
  int tid = threadIdx.x;
#pragma unroll
  for (int it = 0; it < 4; ++it) {
    int f = it * 256 + tid;
    int r = f >> 4, c4 = (f & 15) << 2;
    float4 v = *reinterpret_cast<const float4*>(&src[(size_t)(tm + r) * N + tn + c4]);
    t[c4][r] = v.x; t[c4 + 1][r] = v.y; t[c4 + 2][r] = v.z; t[c4 + 3][r] = v.w;
  }
  __syncthreads();
#pragma unroll
  for (int it = 0; it < 4; ++it) {
    int f = it * 256 + tid;
    int rr = f >> 4, c4 = (f & 15) << 2;
    short4 o;
    o.x = f2bf(t[rr][c4]); o.y = f2bf(t[rr][c4 + 1]);
    o.z = f2bf(t[rr][c4 + 2]); o.w = f2bf(t[rr][c4 + 3]);
    *reinterpret_cast<short4*>(&dst[(size_t)(tn + rr) * M + tm + c4]) = o;
  }
}

// ---------------- Gather selected tokens + cvt to bf16: Xsel[be][k][d] ----------------
__global__ __launch_bounds__(256) void gather_cvt_kernel(const float* __restrict__ x,
                                                         const int* __restrict__ idxArr,
                                                         unsigned short* __restrict__ Xsel) {
  int row = blockIdx.x * 4 + (threadIdx.x >> 6);  // be*K_ + k
  int lane = threadIdx.x & 63;
  int b = row >> 13;                              // be>>3
  int tok = idxArr[row];
  const float* src = x + ((size_t)b * S_ + tok) * D_;
  unsigned short* dst = Xsel + (size_t)row * D_;
#pragma unroll
  for (int it = 0; it < 4; ++it) {
    int d = it * 256 + lane * 4;
    float4 v = *reinterpret_cast<const float4*>(src + d);
    short4 o;
    o.x = f2bf(v.x); o.y = f2bf(v.y); o.z = f2bf(v.z); o.w = f2bf(v.w);
    *reinterpret_cast<short4*>(dst + d) = o;
  }
}

// ---------------- Stage 1: H = silu(Xsel@Wg) * (Xsel@Wu), all-DMA staging ----------------
// kc selects token half: rows [kc*512, kc*512+512). H layout [be][512][I_].
__global__ __launch_bounds__(256, 2) void mlp1_kernel(
    const unsigned short* __restrict__ Xsel, const unsigned short* __restrict__ WgT,
    const unsigned short* __restrict__ WuT, unsigned short* __restrict__ H, int kc) {
  int nwg = gridDim.x;
  int bid = (blockIdx.x & 7) * (nwg >> 3) + (blockIdx.x >> 3);  // XCD swizzle (nwg%8==0)
  int nt = bid & 15; bid >>= 4;        // 16 I-tiles of 128
  int mt = bid & 3; bid >>= 2;         // 4 token-tiles of 128
  int be = bid;
  int e = be & 7;

  __shared__ short lsA[128 * 64];
  __shared__ short lsBg[128 * 64];
  __shared__ short lsBu[128 * 64];

  int tid = threadIdx.x, w = tid >> 6, lane = tid & 63;
  int wm = w >> 1, wn = w & 1;
  int lr = lane & 15, lg = lane >> 4;

  int srow = lane >> 3;                      // row within 8-row chunk
  int scol = ((lane & 7) ^ srow) << 4;       // pre-swizzled source byte col

  const char* pa = (const char*)(Xsel + ((size_t)be * K_ + kc * 512 + mt * 128) * D_);
  const char* pg = (const char*)(WgT + ((size_t)e * I_ + nt * 128) * D_);
  const char* pu = (const char*)(WuT + ((size_t)e * I_ + nt * 128) * D_);

  f32x4 accg[4][4], accu[4][4];
#pragma unroll
  for (int i = 0; i < 4; ++i)
#pragma unroll
    for (int j = 0; j < 4; ++j) {
      accg[i][j] = (f32x4){0.f, 0.f, 0.f, 0.f};
      accu[i][j] = (f32x4){0.f, 0.f, 0.f, 0.f};
    }

  for (int k0 = 0; k0 < D_; k0 += 64) {
#pragma unroll
    for (int c = 0; c < 4; ++c) {
      int chunk = c * 4 + w;                 // wave-uniform
      int row = chunk * 8 + srow;
      size_t go = (size_t)row * (D_ * 2) + (size_t)k0 * 2 + scol;
      gload16(pa + go, (char*)lsA + chunk * 1024);
      gload16(pg + go, (char*)lsBg + chunk * 1024);
      gload16(pu + go, (char*)lsBu + chunk * 1024);
    }
    __syncthreads();
#pragma unroll
    for (int fk = 0; fk < 2; ++fk) {
      int cb = fk * 64 + lg * 16;
      short8 af[4], bgf[4], buf[4];
#pragma unroll
      for (int fm = 0; fm < 4; ++fm)
        af[fm] = rdswz(lsA, wm * 64 + fm * 16 + lr, cb);
#pragma unroll
      for (int fn = 0; fn < 4; ++fn) {
        bgf[fn] = rdswz(lsBg, wn * 64 + fn * 16 + lr, cb);
        buf[fn] = rdswz(lsBu, wn * 64 + fn * 16 + lr, cb);
      }
#pragma unroll
      for (int fm = 0; fm < 4; ++fm)
#pragma unroll
        for (int fn = 0; fn < 4; ++fn) {
          accg[fm][fn] = __builtin_amdgcn_mfma_f32_16x16x32_bf16(af[fm], bgf[fn], accg[fm][fn], 0, 0, 0);
          accu[fm][fn] = __builtin_amdgcn_mfma_f32_16x16x32_bf16(af[fm], buf[fn], accu[fm][fn], 0, 0, 0);
        }
    }
    __syncthreads();
  }
  // epilogue: h = silu(g)*u -> bf16 H[be][512][I_]
  unsigned short* Hbe = H + (size_t)be * 512 * I_;
#pragma unroll
  for (int fm = 0; fm < 4; ++fm)
#pragma unroll
    for (int fn = 0; fn < 4; ++fn) {
#pragma unroll
      for (int j = 0; j < 4; ++j) {
        float g = accg[fm][fn][j], u = accu[fm][fn][j];
        float h = g / (1.f + __expf(-g)) * u;
        int row = wm * 64 + fm * 16 + lg * 4 + j;
        int col = wn * 64 + fn * 16 + lr;
        Hbe[(size_t)(mt * 128 + row) * I_ + nt * 128 + col] = (unsigned short)f2bf(h);
      }
    }
}

// ---------- Stage 2: Out += gate * (H @ Wd), 128x256 tile, full-I reduce ----------
// 4 waves in 2x2; each wave owns 64 rows x 128 cols; acc[4][8].
__global__ __launch_bounds__(256, 2) void mlp2_kernel(
    const unsigned short* __restrict__ H, const unsigned short* __restrict__ WdT,
    const int* __restrict__ idxArr, const float* __restrict__ gateArr,
    float* __restrict__ out, int kc) {
  int nwg = gridDim.x;
  int bid = (blockIdx.x & 7) * (nwg >> 3) + (blockIdx.x >> 3);  // XCD swizzle
  int nt = bid & 3; bid >>= 2;         // 4 D-tiles of 256
  int mt = bid & 3; bid >>= 2;         // 4 token-tiles of 128
  int be = bid;
  int b = be >> 3, e = be & 7;

  __shared__ short lsA[128 * 64];
  __shared__ short lsB[256 * 64];
  __shared__ int sTok[128];
  __shared__ float sGate[128];

  int tid = threadIdx.x;
  if (tid < 128) {
    size_t gbase = (size_t)be * K_ + kc * 512 + mt * 128 + tid;
    sTok[tid] = idxArr[gbase];
    sGate[tid] = gateArr[gbase];
  }

  const char* pa = (const char*)(H + ((size_t)be * 512 + mt * 128) * I_);
  const char* pb = (const char*)(WdT + ((size_t)e * D_ + nt * 256) * I_);

  int w = tid >> 6, lane = tid & 63;
  int wm = w >> 1, wn = w & 1;
  int lr = lane & 15, lg = lane >> 4;

  int srow = lane >> 3;
  int scol = ((lane & 7) ^ srow) << 4;

  f32x4 acc[4][8];
#pragma unroll
  for (int i = 0; i < 4; ++i)
#pragma unroll
    for (int j = 0; j < 8; ++j) acc[i][j] = (f32x4){0.f, 0.f, 0.f, 0.f};

  for (int k0 = 0; k0 < I_; k0 += 64) {
#pragma unroll
    for (int c = 0; c < 4; ++c) {          // A: 16 chunks of 8 rows
      int chunk = c * 4 + w;
      int row = chunk * 8 + srow;
      gload16(pa + (size_t)row * (I_ * 2) + (size_t)k0 * 2 + scol, (char*)lsA + chunk * 1024);
    }
#pragma unroll
    for (int c = 0; c < 8; ++c) {          // B: 32 chunks of 8 rows
      int chunk = c * 4 + w;
      int row = chunk * 8 + srow;
      gload16(pb + (size_t)row * (I_ * 2) + (size_t)k0 * 2 + scol, (char*)lsB + chunk * 1024);
    }
    __syncthreads();
#pragma unroll
    for (int fk = 0; fk < 2; ++fk) {
      int cb = fk * 64 + lg * 16;
      short8 af[4], bf[8];
#pragma unroll
      for (int fm = 0; fm < 4; ++fm)
        af[fm] = rdswz(lsA, wm * 64 + fm * 16 + lr, cb);
#pragma unroll
      for (int fn = 0; fn < 8; ++fn)
        bf[fn] = rdswz(lsB, wn * 128 + fn * 16 + lr, cb);
#pragma unroll
      for (int fm = 0; fm < 4; ++fm)
#pragma unroll
        for (int fn = 0; fn < 8; ++fn)
          acc[fm][fn] = __builtin_amdgcn_mfma_f32_16x16x32_bf16(af[fm], bf[fn], acc[fm][fn], 0, 0, 0);
    }
    __syncthreads();
  }
  // epilogue: weighted scatter-add (once per token per kc half)
#pragma unroll
  for (int fm = 0; fm < 4; ++fm)
#pragma unroll
    for (int fn = 0; fn < 8; ++fn) {
#pragma unroll
      for (int j = 0; j < 4; ++j) {
        int row = wm * 64 + fm * 16 + lg * 4 + j;
        int col = nt * 256 + wn * 128 + fn * 16 + lr;
        float v = acc[fm][fn][j] * sGate[row];
        atomicAdd(&out[((size_t)b * S_ + sTok[row]) * D_ + col], v);
      }
    }
}

extern "C" void kernel_launch(void* const* d_in, const int* in_sizes, int n_in,
                              void* d_out, int out_size, void* d_ws, size_t ws_size,
                              hipStream_t stream) {
  const float* x  = (const float*)d_in[0];
  const float* gw = (const float*)d_in[1];
  const float* Wg = (const float*)d_in[2];
  const float* Wu = (const float*)d_in[3];
  const float* Wd = (const float*)d_in[4];
  float* out = (float*)d_out;
  char* ws = (char*)d_ws;

  size_t off = 0;
  double* affD = (double*)(ws + off); off += (size_t)B_ * E_ * S_ * sizeof(double);  // 1 MB
  int* idxArr = (int*)(ws + off);     off += (size_t)B_ * E_ * K_ * sizeof(int);     // 128 KB
  float* gateArr = (float*)(ws + off); off += (size_t)B_ * E_ * K_ * sizeof(float);  // 128 KB
  off = (off + 255) & ~(size_t)255;
  unsigned short* WgT = (unsigned short*)(ws + off); off += (size_t)E_ * D_ * I_ * 2; // 32 MB
  unsigned short* WuT = (unsigned short*)(ws + off); off += (size_t)E_ * D_ * I_ * 2; // 32 MB
  unsigned short* WdT = (unsigned short*)(ws + off); off += (size_t)E_ * D_ * I_ * 2; // 32 MB
  unsigned short* Xsel = (unsigned short*)(ws + off); off += (size_t)B_ * E_ * K_ * D_ * 2; // 64 MB
  off = (off + 255) & ~(size_t)255;
  unsigned short* H = (unsigned short*)(ws + off);   // 64 MB: [32 be][512 tok][2048 I]

  hipMemsetAsync(d_out, 0, (size_t)out_size * sizeof(float), stream);
  router_kernel<<<B_ * S_ / 4, 256, 0, stream>>>(x, gw, affD);
  topk_select_kernel<<<B_ * E_, 1024, 0, stream>>>(affD, idxArr, gateArr);
  transpose_cvt3_kernel<<<dim3((D_ / 64) * (I_ / 64), 3 * E_), 256, 0, stream>>>(
      Wg, Wu, Wd, WgT, WuT, WdT);
  gather_cvt_kernel<<<B_ * E_ * K_ / 4, 256, 0, stream>>>(x, idxArr, Xsel);
  for (int kc = 0; kc < 2; ++kc) {
    mlp1_kernel<<<B_ * E_ * 4 * 16, 256, 0, stream>>>(Xsel, WgT, WuT, H, kc);
    mlp2_kernel<<<B_ * E_ * 4 * 4, 256, 0, stream>>>(H, WdT, idxArr, gateArr, out, kc);
  }
}